// Round 1
// baseline (520.292 us; speedup 1.0000x reference)
//
#include <hip/hip_runtime.h>
#include <math.h>

#define N_TOK   16384
#define D_MODEL 4096
#define N_EXP   16
#define N_SEL   4
#define DSPLIT  4
#define TB      64      // tokens per block (kernel A)
#define DCH     128     // d-chunk per stage
#define TPB     256

// ---------------------------------------------------------------------------
// Kernel A: dots[ds][t][0..15] = x[t,:]·w1[e,:], dots[ds][t][16..31] = x[t,:]·wn[e,:]
// (partial over d-range of this ds; summed in kernel B)
// ---------------------------------------------------------------------------
__global__ __launch_bounds__(TPB) void gemv_kernel(
    const float* __restrict__ x, const float* __restrict__ w1,
    const float* __restrict__ wn, float* __restrict__ dots)
{
    __shared__ float4 xs[TB * (DCH / 4)];   // 64 x 32 float4 = 32 KB, xor-swizzled

    const int tid  = threadIdx.x;
    const int bid  = blockIdx.x;
    const int tb   = bid >> 2;              // token block 0..255
    const int ds   = bid & 3;               // d split 0..3
    const int t0   = tb * TB;
    const int tt   = tid & 63;              // token within block
    const int slot = __builtin_amdgcn_readfirstlane(tid >> 6);  // wave-uniform 0..3

    // slot 0: w1 rows 0-7, slot 1: w1 rows 8-15, slot 2: wn rows 0-7, slot 3: wn 8-15
    const float* wbase = (slot < 2) ? (w1 + slot * 8 * D_MODEL)
                                    : (wn + (slot - 2) * 8 * D_MODEL);

    float4 acc[8];
    #pragma unroll
    for (int e = 0; e < 8; ++e) acc[e] = make_float4(0.f, 0.f, 0.f, 0.f);

    const int dbase = ds * (D_MODEL / DSPLIT);   // 1024 per split

    for (int c = 0; c < (D_MODEL / DSPLIT) / DCH; ++c) {   // 8 chunks
        const int dg = dbase + c * DCH;

        // ---- stage x[t0..t0+63][dg..dg+127] into LDS (swizzled) ----
        #pragma unroll
        for (int k = 0; k < (TB * DCH / 4) / TPB; ++k) {   // 8 float4 per thread
            const int i  = tid + TPB * k;
            const int r  = i >> 5;          // row 0..63
            const int cg = i & 31;          // float4 column 0..31
            float4 v = *(const float4*)(x + (size_t)(t0 + r) * D_MODEL + dg + cg * 4);
            xs[r * 32 + (cg ^ (r & 7))] = v;
        }
        __syncthreads();

        // ---- accumulate 8 outputs over this chunk ----
        #pragma unroll 4
        for (int cg = 0; cg < 32; ++cg) {
            const float4 xv = xs[tt * 32 + (cg ^ (tt & 7))];
            const float* wp = wbase + dg + cg * 4;
            #pragma unroll
            for (int e = 0; e < 8; ++e) {
                const float4 wv = *(const float4*)(wp + e * D_MODEL);
                acc[e].x = fmaf(xv.x, wv.x, acc[e].x);
                acc[e].y = fmaf(xv.y, wv.y, acc[e].y);
                acc[e].z = fmaf(xv.z, wv.z, acc[e].z);
                acc[e].w = fmaf(xv.w, wv.w, acc[e].w);
            }
        }
        __syncthreads();
    }

    float* dst = dots + ((size_t)ds * N_TOK + (t0 + tt)) * 32 + slot * 8;
    float s[8];
    #pragma unroll
    for (int e = 0; e < 8; ++e)
        s[e] = (acc[e].x + acc[e].y) + (acc[e].z + acc[e].w);
    *(float4*)(dst)     = make_float4(s[0], s[1], s[2], s[3]);
    *(float4*)(dst + 4) = make_float4(s[4], s[5], s[6], s[7]);
}

// ---------------------------------------------------------------------------
// Kernel B: per-token gating epilogue
// ---------------------------------------------------------------------------
__global__ __launch_bounds__(256) void epilogue_kernel(
    const float* __restrict__ dots, const float* __restrict__ w2,
    const float* __restrict__ noise, float* __restrict__ out,
    float* __restrict__ g_imp, float* __restrict__ g_load)
{
    __shared__ float s_imp[N_EXP];
    __shared__ float s_ld[N_EXP];
    const int tid = threadIdx.x;
    if (tid < N_EXP) { s_imp[tid] = 0.f; s_ld[tid] = 0.f; }
    __syncthreads();

    const int t = blockIdx.x * 256 + tid;

    // sum the DSPLIT partial dot products
    float4 a[8];
    #pragma unroll
    for (int j = 0; j < 8; ++j)
        a[j] = ((const float4*)dots)[(size_t)t * 8 + j];
    #pragma unroll
    for (int ds = 1; ds < DSPLIT; ++ds) {
        #pragma unroll
        for (int j = 0; j < 8; ++j) {
            float4 b = ((const float4*)dots)[((size_t)ds * N_TOK + t) * 8 + j];
            a[j].x += b.x; a[j].y += b.y; a[j].z += b.z; a[j].w += b.w;
        }
    }
    float dot[32];
    #pragma unroll
    for (int j = 0; j < 8; ++j) {
        dot[4 * j + 0] = a[j].x; dot[4 * j + 1] = a[j].y;
        dot[4 * j + 2] = a[j].z; dot[4 * j + 3] = a[j].w;
    }

    // tanh(h) and noise_control = softplus(xn) + eps
    float th[N_EXP], nc[N_EXP];
    #pragma unroll
    for (int e = 0; e < N_EXP; ++e) th[e] = tanhf(dot[e]);
    #pragma unroll
    for (int e = 0; e < N_EXP; ++e) {
        const float v = dot[N_EXP + e];
        nc[e] = fmaxf(v, 0.f) + log1pf(expf(-fabsf(v))) + 0.01f;
    }

    // logits_gate = tanh(h) @ w2^T    (w2[f][e], 16x16)
    float lg[N_EXP];
    #pragma unroll
    for (int f = 0; f < N_EXP; ++f) {
        float s = 0.f;
        #pragma unroll
        for (int e = 0; e < N_EXP; ++e) s = fmaf(th[e], w2[f * 16 + e], s);
        lg[f] = s;
    }

    // logits = logits_gate + noise * noise_control
    float ln[N_EXP], v[N_EXP];
    {
        const float4* nz = (const float4*)(noise + (size_t)t * 16);
        float4 n0 = nz[0], n1 = nz[1], n2 = nz[2], n3 = nz[3];
        float nzv[16] = {n0.x, n0.y, n0.z, n0.w, n1.x, n1.y, n1.z, n1.w,
                         n2.x, n2.y, n2.z, n2.w, n3.x, n3.y, n3.z, n3.w};
        #pragma unroll
        for (int e = 0; e < N_EXP; ++e) {
            ln[e] = nzv[e] * nc[e];
            v[e]  = lg[e] + ln[e];
        }
    }

    // top-5 selection (ties -> lowest index, matching lax.top_k)
    float tv[5]; int ti[5];
    #pragma unroll
    for (int j = 0; j < 5; ++j) {
        float best = -INFINITY; int bi = 0;
        #pragma unroll
        for (int e = 0; e < N_EXP; ++e) {
            bool taken = false;
            #pragma unroll
            for (int jj = 0; jj < 5; ++jj)
                if (jj < j) taken = taken || (ti[jj] == e);
            if (!taken && v[e] > best) { best = v[e]; bi = e; }
        }
        tv[j] = best; ti[j] = bi;
    }

    // softmax over top-4
    const float m = tv[0];
    float ex[4], ssum = 0.f;
    #pragma unroll
    for (int j = 0; j < 4; ++j) { ex[j] = expf(tv[j] - m); ssum += ex[j]; }
    const float inv = 1.f / ssum;
    float sc[4];
    #pragma unroll
    for (int j = 0; j < 4; ++j) sc[j] = ex[j] * inv;

    // importance accumulation
    #pragma unroll
    for (int j = 0; j < 4; ++j) atomicAdd(&s_imp[ti[j]], sc[j]);

    // load: P(in top-k) via normal CDF
    const float thr_in = tv[4], thr_out = tv[3];
    #pragma unroll
    for (int e = 0; e < N_EXP; ++e) {
        const bool is_in = ln[e] > thr_in;
        const float thr = is_in ? thr_in : thr_out;
        const float z = (lg[e] - thr) / nc[e];
        const float prob = 0.5f * (1.f + erff(z * 0.70710678118654752f));
        atomicAdd(&s_ld[e], prob);
    }

    // outputs: indices (as float) then scores
    ((float4*)out)[t] = make_float4((float)ti[0], (float)ti[1],
                                    (float)ti[2], (float)ti[3]);
    ((float4*)(out + N_TOK * N_SEL))[t] = make_float4(sc[0], sc[1], sc[2], sc[3]);

    __syncthreads();
    if (tid < N_EXP) {
        atomicAdd(&g_imp[tid], s_imp[tid]);
        atomicAdd(&g_load[tid], s_ld[tid]);
    }
}

// ---------------------------------------------------------------------------
// Kernel C: gate loss = lambda * (cv2(importance) + cv2(load))
// ---------------------------------------------------------------------------
__global__ void loss_kernel(const float* __restrict__ g_imp,
                            const float* __restrict__ g_load,
                            float* __restrict__ out)
{
    if (threadIdx.x == 0 && blockIdx.x == 0) {
        double mi = 0.0, ml = 0.0;
        for (int e = 0; e < N_EXP; ++e) { mi += g_imp[e]; ml += g_load[e]; }
        mi /= N_EXP; ml /= N_EXP;
        double vi = 0.0, vl = 0.0;
        for (int e = 0; e < N_EXP; ++e) {
            const double di = g_imp[e] - mi;  vi += di * di;
            const double dl = g_load[e] - ml; vl += dl * dl;
        }
        vi /= (N_EXP - 1); vl /= (N_EXP - 1);
        const double ci = vi / (mi * mi + 1e-10);
        const double cl = vl / (ml * ml + 1e-10);
        out[N_TOK * N_SEL * 2] = (float)(0.01 * (ci + cl));
    }
}

// ---------------------------------------------------------------------------
extern "C" void kernel_launch(void* const* d_in, const int* in_sizes, int n_in,
                              void* d_out, int out_size, void* d_ws, size_t ws_size,
                              hipStream_t stream)
{
    const float* x     = (const float*)d_in[0];
    const float* w1    = (const float*)d_in[1];
    const float* w2    = (const float*)d_in[2];
    const float* wn    = (const float*)d_in[3];
    const float* noise = (const float*)d_in[4];
    float* out = (float*)d_out;

    float* dots   = (float*)d_ws;                          // DSPLIT*16384*32 floats = 8 MB
    float* g_imp  = dots + (size_t)DSPLIT * N_TOK * 32;    // 16 floats
    float* g_load = g_imp + N_EXP;                         // 16 floats

    hipMemsetAsync(g_imp, 0, 2 * N_EXP * sizeof(float), stream);

    gemv_kernel<<<256 * DSPLIT, TPB, 0, stream>>>(x, w1, wn, dots);
    epilogue_kernel<<<N_TOK / 256, 256, 0, stream>>>(dots, w2, noise, out,
                                                     g_imp, g_load);
    loss_kernel<<<1, 64, 0, stream>>>(g_imp, g_load, out);
}

// Round 2
// 436.796 us; speedup vs baseline: 1.1912x; 1.1912x over previous
//
#include <hip/hip_runtime.h>
#include <math.h>

#define N_TOK   16384
#define D_MODEL 4096
#define N_EXP   16
#define N_SEL   4
#define WELEM   (N_EXP * D_MODEL)   // 65536 per weight matrix

typedef __bf16 bf16x8 __attribute__((ext_vector_type(8)));
typedef float  f32x4  __attribute__((ext_vector_type(4)));

#define MFMA(a, b, c) __builtin_amdgcn_mfma_f32_16x16x32_bf16((a), (b), (c), 0, 0, 0)

// ---------------------------------------------------------------------------
// Split w1/wn into bf16 (hi, mid, lo) triplets: w ≈ hi + mid + lo, residual
// ≤ 2^-24 relative. Layout in wbuf: [w1hi][w1mid][w1lo][wnhi][wnmid][wnlo].
// ---------------------------------------------------------------------------
__global__ __launch_bounds__(256) void wprep_kernel(const float* __restrict__ w1,
                                                    const float* __restrict__ wn,
                                                    __bf16* __restrict__ wbuf)
{
    const int i = blockIdx.x * 256 + threadIdx.x;   // 0..65535
    {
        const float v = w1[i];
        const __bf16 h = (__bf16)v;  const float r1 = v - (float)h;
        const __bf16 m = (__bf16)r1; const float r2 = r1 - (float)m;
        wbuf[i] = h; wbuf[WELEM + i] = m; wbuf[2 * WELEM + i] = (__bf16)r2;
    }
    {
        const float v = wn[i];
        const __bf16 h = (__bf16)v;  const float r1 = v - (float)h;
        const __bf16 m = (__bf16)r1; const float r2 = r1 - (float)m;
        wbuf[3 * WELEM + i] = h; wbuf[4 * WELEM + i] = m; wbuf[5 * WELEM + i] = (__bf16)r2;
    }
}

// ---------------------------------------------------------------------------
// Fused gate kernel: block = 16 tokens, 4 waves (k-split 1024 each).
// Wave computes two 16x16 C-tiles (w1 rows, wn rows) via split-bf16 MFMA.
// A-frag: A[m=lane&15][k=(lane>>4)*8+j]; B-frag: B[k=(lane>>4)*8+j][n=lane&15];
// C/D: col(token)=lane&15, row(expert)=(lane>>4)*4+reg.   (HW-verified layouts)
// ---------------------------------------------------------------------------
__global__ __launch_bounds__(256) void gate_kernel(
    const float* __restrict__ x, const __bf16* __restrict__ wbuf,
    const float* __restrict__ w2, const float* __restrict__ noise,
    float* __restrict__ out, float* __restrict__ g_imp, float* __restrict__ g_load)
{
    __shared__ float red[4][16][32];
    __shared__ float dsum[16][32];
    __shared__ float s_imp[N_EXP], s_ld[N_EXP];

    const int tid  = threadIdx.x;
    const int lane = tid & 63;
    const int wv   = tid >> 6;
    const int ml   = lane & 15;     // A-row / B-col / token-within-tile
    const int q    = lane >> 4;     // k-group
    const int t0   = blockIdx.x * 16;

    const __bf16* w1h = wbuf;
    const __bf16* w1m = wbuf + WELEM;
    const __bf16* w1l = wbuf + 2 * WELEM;
    const __bf16* wnh = wbuf + 3 * WELEM;
    const __bf16* wnm = wbuf + 4 * WELEM;
    const __bf16* wnl = wbuf + 5 * WELEM;

    const size_t xoff = (size_t)(t0 + ml) * D_MODEL + wv * 1024 + q * 8;
    const int    woff = ml * D_MODEL + wv * 1024 + q * 8;

    f32x4 c1 = {0.f, 0.f, 0.f, 0.f};
    f32x4 c2 = {0.f, 0.f, 0.f, 0.f};

    #pragma unroll 2
    for (int it = 0; it < 32; ++it) {
        const int ko = it * 32;
        const float4 xa = *(const float4*)(x + xoff + ko);
        const float4 xb = *(const float4*)(x + xoff + ko + 4);
        const bf16x8 a1h = *(const bf16x8*)(w1h + woff + ko);
        const bf16x8 a1m = *(const bf16x8*)(w1m + woff + ko);
        const bf16x8 a1l = *(const bf16x8*)(w1l + woff + ko);
        const bf16x8 a2h = *(const bf16x8*)(wnh + woff + ko);
        const bf16x8 a2m = *(const bf16x8*)(wnm + woff + ko);
        const bf16x8 a2l = *(const bf16x8*)(wnl + woff + ko);

        const float xv[8] = {xa.x, xa.y, xa.z, xa.w, xb.x, xb.y, xb.z, xb.w};
        bf16x8 xh, xm8, xl;
        #pragma unroll
        for (int j = 0; j < 8; ++j) {
            const float v  = xv[j];
            const __bf16 h = (__bf16)v;   const float r1 = v - (float)h;
            const __bf16 md = (__bf16)r1; const float r2 = r1 - (float)md;
            xh[j] = h; xm8[j] = md; xl[j] = (__bf16)r2;
        }

        c1 = MFMA(a1h, xh, c1);  c1 = MFMA(a1h, xm8, c1); c1 = MFMA(a1m, xh, c1);
        c1 = MFMA(a1h, xl, c1);  c1 = MFMA(a1l, xh, c1);  c1 = MFMA(a1m, xm8, c1);
        c2 = MFMA(a2h, xh, c2);  c2 = MFMA(a2h, xm8, c2); c2 = MFMA(a2m, xh, c2);
        c2 = MFMA(a2h, xl, c2);  c2 = MFMA(a2l, xh, c2);  c2 = MFMA(a2m, xm8, c2);
    }

    #pragma unroll
    for (int r = 0; r < 4; ++r) {
        red[wv][ml][q * 4 + r]      = c1[r];
        red[wv][ml][16 + q * 4 + r] = c2[r];
    }
    __syncthreads();

    for (int idx = tid; idx < 512; idx += 256) {
        const int tk = idx >> 5, o = idx & 31;
        dsum[tk][o] = red[0][tk][o] + red[1][tk][o] + red[2][tk][o] + red[3][tk][o];
    }
    if (tid < N_EXP) { s_imp[tid] = 0.f; s_ld[tid] = 0.f; }
    __syncthreads();

    // ---- per-token epilogue on 16 lanes ----
    if (tid < 16) {
        const int t = t0 + tid;
        float dot[32];
        #pragma unroll
        for (int e = 0; e < 32; ++e) dot[e] = dsum[tid][e];

        float th[N_EXP], nc[N_EXP];
        #pragma unroll
        for (int e = 0; e < N_EXP; ++e) th[e] = tanhf(dot[e]);
        #pragma unroll
        for (int e = 0; e < N_EXP; ++e) {
            const float v = dot[N_EXP + e];
            nc[e] = fmaxf(v, 0.f) + log1pf(expf(-fabsf(v))) + 0.01f;
        }

        float lg[N_EXP];
        #pragma unroll
        for (int f = 0; f < N_EXP; ++f) {
            float s = 0.f;
            #pragma unroll
            for (int e = 0; e < N_EXP; ++e) s = fmaf(th[e], w2[f * 16 + e], s);
            lg[f] = s;
        }

        float ln[N_EXP], v[N_EXP];
        {
            const float4* nz = (const float4*)(noise + (size_t)t * 16);
            const float4 n0 = nz[0], n1 = nz[1], n2 = nz[2], n3 = nz[3];
            const float nzv[16] = {n0.x, n0.y, n0.z, n0.w, n1.x, n1.y, n1.z, n1.w,
                                   n2.x, n2.y, n2.z, n2.w, n3.x, n3.y, n3.z, n3.w};
            #pragma unroll
            for (int e = 0; e < N_EXP; ++e) {
                ln[e] = nzv[e] * nc[e];
                v[e]  = lg[e] + ln[e];
            }
        }

        // top-5 selection (ties -> lowest index, matching lax.top_k)
        float tv[5]; int ti[5];
        #pragma unroll
        for (int j = 0; j < 5; ++j) {
            float best = -INFINITY; int bi = 0;
            #pragma unroll
            for (int e = 0; e < N_EXP; ++e) {
                bool taken = false;
                #pragma unroll
                for (int jj = 0; jj < 5; ++jj)
                    if (jj < j) taken = taken || (ti[jj] == e);
                if (!taken && v[e] > best) { best = v[e]; bi = e; }
            }
            tv[j] = best; ti[j] = bi;
        }

        const float mx = tv[0];
        float ex[4], ssum = 0.f;
        #pragma unroll
        for (int j = 0; j < 4; ++j) { ex[j] = expf(tv[j] - mx); ssum += ex[j]; }
        const float inv = 1.f / ssum;
        float sc[4];
        #pragma unroll
        for (int j = 0; j < 4; ++j) sc[j] = ex[j] * inv;

        #pragma unroll
        for (int j = 0; j < 4; ++j) atomicAdd(&s_imp[ti[j]], sc[j]);

        const float thr_in = tv[4], thr_out = tv[3];
        #pragma unroll
        for (int e = 0; e < N_EXP; ++e) {
            const bool  is_in = ln[e] > thr_in;
            const float thr   = is_in ? thr_in : thr_out;
            const float z     = (lg[e] - thr) / nc[e];
            const float prob  = 0.5f * (1.f + erff(z * 0.70710678118654752f));
            atomicAdd(&s_ld[e], prob);
        }

        ((float4*)out)[t] = make_float4((float)ti[0], (float)ti[1],
                                        (float)ti[2], (float)ti[3]);
        ((float4*)(out + N_TOK * N_SEL))[t] = make_float4(sc[0], sc[1], sc[2], sc[3]);
    }
    __syncthreads();
    if (tid < N_EXP)            atomicAdd(&g_imp[tid], s_imp[tid]);
    else if (tid < 2 * N_EXP)   atomicAdd(&g_load[tid - N_EXP], s_ld[tid - N_EXP]);
}

// ---------------------------------------------------------------------------
// gate loss = lambda * (cv2(importance) + cv2(load))
// ---------------------------------------------------------------------------
__global__ void loss_kernel(const float* __restrict__ g_imp,
                            const float* __restrict__ g_load,
                            float* __restrict__ out)
{
    if (threadIdx.x == 0 && blockIdx.x == 0) {
        double mi = 0.0, ml = 0.0;
        for (int e = 0; e < N_EXP; ++e) { mi += g_imp[e]; ml += g_load[e]; }
        mi /= N_EXP; ml /= N_EXP;
        double vi = 0.0, vl = 0.0;
        for (int e = 0; e < N_EXP; ++e) {
            const double di = g_imp[e] - mi;  vi += di * di;
            const double dl = g_load[e] - ml; vl += dl * dl;
        }
        vi /= (N_EXP - 1); vl /= (N_EXP - 1);
        const double ci = vi / (mi * mi + 1e-10);
        const double cl = vl / (ml * ml + 1e-10);
        out[N_TOK * N_SEL * 2] = (float)(0.01 * (ci + cl));
    }
}

// ---------------------------------------------------------------------------
extern "C" void kernel_launch(void* const* d_in, const int* in_sizes, int n_in,
                              void* d_out, int out_size, void* d_ws, size_t ws_size,
                              hipStream_t stream)
{
    const float* x     = (const float*)d_in[0];
    const float* w1    = (const float*)d_in[1];
    const float* w2    = (const float*)d_in[2];
    const float* wn    = (const float*)d_in[3];
    const float* noise = (const float*)d_in[4];
    float* out = (float*)d_out;

    __bf16* wbuf  = (__bf16*)d_ws;                              // 6*65536 bf16 = 768 KB
    float*  g_imp = (float*)((char*)d_ws + (1 << 20));          // 16 floats @ 1 MB
    float*  g_load = g_imp + N_EXP;

    hipMemsetAsync(g_imp, 0, 2 * N_EXP * sizeof(float), stream);

    wprep_kernel<<<WELEM / 256, 256, 0, stream>>>(w1, wn, wbuf);
    gate_kernel<<<N_TOK / 16, 256, 0, stream>>>(x, wbuf, w2, noise, out,
                                                g_imp, g_load);
    loss_kernel<<<1, 64, 0, stream>>>(g_imp, g_load, out);
}